// Round 17
// baseline (269.492 us; speedup 1.0000x reference)
//
#include <hip/hip_runtime.h>
#include <math.h>

#define NN 50000
#define EE 800000
#define ET 850000    // EE + NN self loops
#define FIN 128
#define HD 64
#define NH 4
#define NGR 64
#define NCL 10
#define NEG 0.2f
#define NBK 196      // buckets = dst>>8
#define ECH 831      // edge chunks of 1024

typedef unsigned short u16;
typedef unsigned char u8;
typedef unsigned int u32;
typedef __attribute__((ext_vector_type(8))) short short8;
typedef __attribute__((ext_vector_type(4))) float f32x4;
typedef __attribute__((ext_vector_type(2))) float f32x2;

__device__ __forceinline__ float lrelu(float x){ return x > 0.f ? x : NEG * x; }

__device__ __forceinline__ float wsum(float v){
#pragma unroll
  for (int o = 32; o > 0; o >>= 1) v += __shfl_xor(v, o, 64);
  return v;
}
__device__ __forceinline__ float wmax(float v){
#pragma unroll
  for (int o = 32; o > 0; o >>= 1) v = fmaxf(v, __shfl_xor(v, o, 64));
  return v;
}
__device__ __forceinline__ int wsumi(int v){
#pragma unroll
  for (int o = 32; o > 0; o >>= 1) v += __shfl_xor(v, o, 64);
  return v;
}
__device__ __forceinline__ int esrc(const int* ei, int e){ return e < EE ? ei[e] : e - EE; }
__device__ __forceinline__ int edst(const int* ei, int e){ return e < EE ? ei[EE + e] : e - EE; }

__device__ __forceinline__ unsigned f2key(float f){
  unsigned u = __float_as_uint(f);
  return (u & 0x80000000u) ? ~u : (u | 0x80000000u);
}
__device__ __forceinline__ float key2f(unsigned k){
  return (k & 0x80000000u) ? __uint_as_float(k & 0x7fffffffu) : __uint_as_float(~k);
}

// bf16 pack (RNE) / unpack
__device__ __forceinline__ u16 f2b(float f){
  u32 u = __float_as_uint(f);
  u32 r = (u + 0x7FFFu + ((u >> 16) & 1u)) >> 16;
  return (u16)r;
}
__device__ __forceinline__ float b2f(u16 b){ return __uint_as_float(((u32)b) << 16); }
__device__ __forceinline__ u32 pkbf16(float lo, float hi){
  u32 r;
  asm("v_cvt_pk_bf16_f32 %0, %1, %2" : "=v"(r) : "v"(lo), "v"(hi));
  return r;
}
// fp8 e4m3 (OCP on gfx950) encode: low byte of packed cvt
__device__ __forceinline__ u8 f2fp8(float f){
  return (u8)__builtin_amdgcn_cvt_pk_fp8_f32(f, 0.f, 0, false);
}
// uniform readlane (idx may be runtime-uniform)
__device__ __forceinline__ int rl(int v, int idx){ return __builtin_amdgcn_readlane(v, idx); }
__device__ __forceinline__ float rlf(float v, int idx){
  return __uint_as_float((u32)__builtin_amdgcn_readlane((int)__float_as_uint(v), idx));
}

// ---------- CSR build pass 1a: per-chunk LDS bucket histogram || zero-init block ----------
__global__ __launch_bounds__(256) void k_b1hist(const int* __restrict__ ei, int* __restrict__ bcnt,
                                                float* __restrict__ zbase, int zcount){
  __shared__ int lc[NBK];
  int t = threadIdx.x, blk = blockIdx.x;
  if (blk >= ECH){
    // zero gsum/gmaxk/gcnt/pdone (visible to k_pool via kernel ordering)
    for (int i = t; i < zcount; i += 256) zbase[i] = 0.f;
    return;
  }
  for (int i = t; i < NBK; i += 256) lc[i] = 0;
  __syncthreads();
#pragma unroll
  for (int k = 0; k < 4; ++k){
    int e = blk*1024 + k*256 + t;
    if (e < ET) atomicAdd(&lc[edst(ei, e) >> 8], 1);
  }
  __syncthreads();
  for (int i = t; i < NBK; i += 256) bcnt[i*ECH + blk] = lc[i];
}

// ---------- pass 1b: bucket totals ----------
__global__ __launch_bounds__(256) void k_bscana(const int* __restrict__ bcnt, int* __restrict__ btot){
  int b = blockIdx.x, t = threadIdx.x;
  int s = 0;
  for (int j = t; j < ECH; j += 256) s += bcnt[b*ECH + j];
  s = wsumi(s);
  __shared__ int w4[4];
  if ((t & 63) == 0) w4[t >> 6] = s;
  __syncthreads();
  if (t == 0) btot[b] = w4[0] + w4[1] + w4[2] + w4[3];
}

// ---------- pass 1c: per-(bucket,chunk) global offsets + bucket bases ----------
__global__ __launch_bounds__(256) void k_bscanb(const int* __restrict__ bcnt, const int* __restrict__ btot,
                                                int* __restrict__ boff, int* __restrict__ bb){
  int b = blockIdx.x, t = threadIdx.x;
  int pv = (t < b) ? btot[t] : 0;       // NBK <= 256
  int r = wsumi(pv);
  __shared__ int w4[4];
  if ((t & 63) == 0) w4[t >> 6] = r;
  __syncthreads();
  int base = w4[0] + w4[1] + w4[2] + w4[3];
  if (t == 0) bb[b] = base;
  __shared__ int s[256];
  int carry = 0;
  for (int j0 = 0; j0 < ECH; j0 += 256){
    int j = j0 + t;
    int v = (j < ECH) ? bcnt[b*ECH + j] : 0;
    s[t] = v; __syncthreads();
    for (int d = 1; d < 256; d <<= 1){
      int xv = (t >= d) ? s[t-d] : 0;
      __syncthreads();
      s[t] += xv;
      __syncthreads();
    }
    int excl = s[t] - v;
    if (j < ECH) boff[b*ECH + j] = base + carry + excl;
    int tot = s[255];
    __syncthreads();
    carry += tot;
  }
}

// ---------- pass 1d: bucket-scatter edges into packed (LDS-atomic local rank only) ----------
__global__ __launch_bounds__(256) void k_b1scat(const int* __restrict__ ei, const int* __restrict__ boff,
                                                u32* __restrict__ packed){
  __shared__ int lpos[NBK];
  int t = threadIdx.x, blk = blockIdx.x;
  for (int i = t; i < NBK; i += 256) lpos[i] = boff[i*ECH + blk];
  __syncthreads();
#pragma unroll
  for (int k = 0; k < 4; ++k){
    int e = blk*1024 + k*256 + t;
    if (e < ET){
      int d = edst(ei, e);
      int s = esrc(ei, e);
      int slot = atomicAdd(&lpos[d >> 8], 1);
      packed[slot] = ((u32)(d & 255) << 16) | (u32)s;
    }
  }
}

// ---------- fused kernel: proj+feat1 GEMM chain || per-bucket CSR finalize ----------
__global__ __launch_bounds__(256) void k_phf2(
            const u32* __restrict__ packed, const int* __restrict__ btot, const int* __restrict__ bb,
            int* __restrict__ off, u16* __restrict__ csrc,
            const float* __restrict__ x, const float* __restrict__ Wp, const float* __restrict__ bp,
            const float* __restrict__ W1, const float* __restrict__ as1, const float* __restrict__ ad1,
            u8* __restrict__ h1f8, float* __restrict__ a_s, float* __restrict__ a_d, int gb){
  __shared__ u16 As[64*(FIN+8)];    // x staging, bf16, LDK1=136
  __shared__ u16 h0s[64*(HD+8)];    // h0 tile,   bf16, LDH=72
  __shared__ int hc[256];
  __shared__ int sc[256];
  __shared__ int pp[256];
  int t = threadIdx.x;
  int bid = blockIdx.x;
  if (bid >= gb){
    // ---- CSR finalize for bucket b ----
    int b = bid - gb;
    int e0 = bb[b];
    int cntb = btot[b];
    hc[t] = 0;
    __syncthreads();
    for (int i = t; i < cntb; i += 256){
      u32 p = packed[e0 + i];
      atomicAdd(&hc[p >> 16], 1);
    }
    __syncthreads();
    int v = hc[t];
    sc[t] = v; __syncthreads();
    for (int d = 1; d < 256; d <<= 1){
      int xv = (t >= d) ? sc[t-d] : 0;
      __syncthreads();
      sc[t] += xv;
      __syncthreads();
    }
    int excl = sc[t] - v;
    int node = b*256 + t;
    if (node < NN) off[node] = e0 + excl;
    if (b == 0 && t == 0) off[NN] = ET;
    pp[t] = excl;
    __syncthreads();
    for (int i = t; i < cntb; i += 256){
      u32 p = packed[e0 + i];
      int slot = atomicAdd(&pp[p >> 16], 1);
      csrc[(size_t)e0 + slot] = (u16)(p & 0xFFFFu);
    }
    return;
  }
  // ---- GEMM chain: h0 = relu(x@Wp+bp) (LDS); h1f8 = fp8(h0@W1); per-head dots ----
  constexpr int LDK1 = FIN + 8;   // 136
  constexpr int LDH  = HD + 8;    // 72
  int w = t >> 6, l = t & 63;
  int l16 = l & 15, kg = l >> 4;

  short8 bfp[4];
#pragma unroll
  for (int kt = 0; kt < 4; ++kt){
    short8 v;
#pragma unroll
    for (int j = 0; j < 8; ++j) v[j] = (short)f2b(Wp[(size_t)(kt*32 + kg*8 + j)*HD + w*16 + l16]);
    bfp[kt] = v;
  }
  short8 bf1[2*4];
#pragma unroll
  for (int kt = 0; kt < 2; ++kt)
#pragma unroll
    for (int nt = 0; nt < 4; ++nt){
      short8 v;
#pragma unroll
      for (int j = 0; j < 8; ++j) v[j] = (short)f2b(W1[(size_t)(kt*32 + kg*8 + j)*256 + w*64 + nt*16 + l16]);
      bf1[kt*4 + nt] = v;
    }
  float bv = bp[w*16 + l16];
  float asv[4], adv[4];
#pragma unroll
  for (int nt = 0; nt < 4; ++nt){
    asv[nt] = as1[w*64 + nt*16 + l16];
    adv[nt] = ad1[w*64 + nt*16 + l16];
  }

  for (int ch = 0; ch < 2; ++ch){
    int nb = (bid*2 + ch)*64;
    if (nb >= NN) break;
    __syncthreads();
    for (int u = t; u < 64*16; u += 256){
      int r = u >> 4, c = u & 15;
      int n = nb + r;
      uint4 v = make_uint4(0u,0u,0u,0u);
      if (n < NN){
        float4 f0 = *(const float4*)&x[(size_t)n*FIN + c*8];
        float4 f1 = *(const float4*)&x[(size_t)n*FIN + c*8 + 4];
        v = make_uint4(pkbf16(f0.x,f0.y), pkbf16(f0.z,f0.w), pkbf16(f1.x,f1.y), pkbf16(f1.z,f1.w));
      }
      *(uint4*)&As[r*LDK1 + c*8] = v;
    }
    __syncthreads();
#pragma unroll
    for (int rt = 0; rt < 4; ++rt){
      short8 afp[4];
#pragma unroll
      for (int kt = 0; kt < 4; ++kt)
        afp[kt] = *(const short8*)&As[(rt*16 + l16)*LDK1 + kt*32 + kg*8];
      f32x4 acc = (f32x4){0.f,0.f,0.f,0.f};
#pragma unroll
      for (int kt = 0; kt < 4; ++kt)
        acc = __builtin_amdgcn_mfma_f32_16x16x32_bf16(afp[kt], bfp[kt], acc, 0, 0, 0);
#pragma unroll
      for (int r4 = 0; r4 < 4; ++r4)
        h0s[(rt*16 + kg*4 + r4)*LDH + w*16 + l16] = f2b(fmaxf(acc[r4] + bv, 0.f));
    }
    __syncthreads();
#pragma unroll
    for (int rt = 0; rt < 4; ++rt){
      short8 af[2];
#pragma unroll
      for (int kt = 0; kt < 2; ++kt)
        af[kt] = *(const short8*)&h0s[(rt*16 + l16)*LDH + kt*32 + kg*8];
      f32x4 acc[4];
#pragma unroll
      for (int nt = 0; nt < 4; ++nt){
        acc[nt] = (f32x4){0.f,0.f,0.f,0.f};
#pragma unroll
        for (int kt = 0; kt < 2; ++kt)
          acc[nt] = __builtin_amdgcn_mfma_f32_16x16x32_bf16(af[kt], bf1[kt*4 + nt], acc[nt], 0, 0, 0);
      }
      int rbase = nb + rt*16 + kg*4;
#pragma unroll
      for (int nt = 0; nt < 4; ++nt)
#pragma unroll
        for (int r4 = 0; r4 < 4; ++r4){
          int n = rbase + r4;
          if (n < NN) h1f8[(size_t)n*256 + w*64 + nt*16 + l16] = f2fp8(acc[nt][r4]);
        }
#pragma unroll
      for (int r4 = 0; r4 < 4; ++r4){
        float ps = 0.f, pd = 0.f;
#pragma unroll
        for (int nt = 0; nt < 4; ++nt){
          ps = fmaf(acc[nt][r4], asv[nt], ps);
          pd = fmaf(acc[nt][r4], adv[nt], pd);
        }
#pragma unroll
        for (int o = 1; o < 16; o <<= 1){
          ps += __shfl_xor(ps, o, 64);
          pd += __shfl_xor(pd, o, 64);
        }
        int n = rbase + r4;
        if (l16 == 0 && n < NN){ a_s[n*NH + w] = ps; a_d[n*NH + w] = pd; }
      }
    }
  }
}

// ---------- MFMA GEMM body (used by feat2): C = A@B, bf16 in/out, fused layer-2 dots ----------
template<int K, int NOUT, int CPW>
__device__ __forceinline__ void gemm_body2(int bid, u16* As, float* sred,
            const u16* __restrict__ A, const float* __restrict__ Bf,
            const float* __restrict__ att_s, const float* __restrict__ att_d,
            u16* __restrict__ C, float* __restrict__ a_s, float* __restrict__ a_d){
  constexpr int KT = K/32;
  constexpr int LDK = K + 8;
  int t = threadIdx.x, w = t >> 6, l = t & 63;
  int c0 = w*CPW;
  int l16 = l & 15, kg = l >> 4;

  short8 bf[KT];
#pragma unroll
  for (int kt = 0; kt < KT; ++kt){
    int kbase = kt*32 + kg*8;
    int col = c0 + l16;
    short8 v;
#pragma unroll
    for (int j = 0; j < 8; ++j) v[j] = (short)f2b(Bf[(size_t)(kbase + j)*NOUT + col]);
    bf[kt] = v;
  }
  float asv = att_s[c0 + l16], adv = att_d[c0 + l16];

  for (int ch = 0; ch < 2; ++ch){
    int nb = (bid*2 + ch)*64;
    if (nb >= NN) break;
    __syncthreads();
    constexpr int UPR = K/8;
    for (int u = t; u < 64*UPR; u += 256){
      int r = u / UPR, c = u % UPR;
      int n = nb + r;
      uint4 v = make_uint4(0u,0u,0u,0u);
      if (n < NN) v = *(const uint4*)&A[(size_t)n*K + c*8];
      *(uint4*)&As[r*LDK + c*8] = v;
    }
    __syncthreads();
#pragma unroll
    for (int rt = 0; rt < 4; ++rt){
      short8 af[KT];
#pragma unroll
      for (int kt = 0; kt < KT; ++kt)
        af[kt] = *(const short8*)&As[(rt*16 + l16)*LDK + kt*32 + kg*8];
      f32x4 acc = (f32x4){0.f,0.f,0.f,0.f};
#pragma unroll
      for (int kt = 0; kt < KT; ++kt)
        acc = __builtin_amdgcn_mfma_f32_16x16x32_bf16(af[kt], bf[kt], acc, 0, 0, 0);
      int rbase = nb + rt*16 + kg*4;
#pragma unroll
      for (int r4 = 0; r4 < 4; ++r4){
        int n = rbase + r4;
        if (n < NN) C[(size_t)n*NOUT + c0 + l16] = f2b(acc[r4]);
      }
#pragma unroll
      for (int r4 = 0; r4 < 4; ++r4){
        float ps = acc[r4]*asv;
        float pd = acc[r4]*adv;
#pragma unroll
        for (int o = 1; o < 16; o <<= 1){
          ps += __shfl_xor(ps, o, 64);
          pd += __shfl_xor(pd, o, 64);
        }
        if (l16 == 0){
          int row = rt*16 + kg*4 + r4;
          sred[(w*64 + row)*2]     = ps;
          sred[(w*64 + row)*2 + 1] = pd;
        }
      }
    }
    __syncthreads();
    if (t < 64){
      int n = nb + t;
      if (n < NN){
        float s = sred[t*2] + sred[(64+t)*2] + sred[(128+t)*2] + sred[(192+t)*2];
        float d = sred[t*2+1] + sred[(64+t)*2+1] + sred[(128+t)*2+1] + sred[(192+t)*2+1];
        a_s[n] = s; a_d[n] = d;
      }
    }
  }
}

// ---------- feat2 GEMM with fused layer-2 dots ----------
__global__ __launch_bounds__(256) void k_feat2(const u16* __restrict__ h1outb, const float* __restrict__ W2,
            const float* __restrict__ as2, const float* __restrict__ ad2,
            u16* __restrict__ h2b, float* __restrict__ a_s, float* __restrict__ a_d){
  __shared__ u16 As[64*(256+8)];
  __shared__ float sred[4*64*2];
  gemm_body2<256, 64, 16>(blockIdx.x, As, sred, h1outb, W2, as2, ad2, h2b, a_s, a_d);
}

// ---------- GAT layer-1 aggregation: wave = node, 256B fp8 row/load, packed cvt ----------
__global__ __launch_bounds__(256) void k_gat1(const u8* __restrict__ h1f8, const float* __restrict__ a_s,
                       const float* __restrict__ a_d, const int* __restrict__ off,
                       const u16* __restrict__ csrc, const float* __restrict__ b1,
                       u16* __restrict__ h1outb){
  __shared__ float lw[4][4][68];   // [wave][head][64 + 4 pad]
  int wv = threadIdx.x >> 6, l = threadIdx.x & 63;
  int n = blockIdx.x*4 + wv;
  if (n >= NN) return;
  int e0 = off[n], e1 = off[n+1], deg = e1 - e0;
  int j16 = l & 15, h = l >> 4;
  float adst = a_d[n*NH + h];
  float acc0 = 0.f, acc1 = 0.f, acc2 = 0.f, acc3 = 0.f;
  const u8* base = h1f8 + 4*l;

#define GAT1_FMA8(wrd, wq) { \
  f32x2 lo_ = __builtin_amdgcn_cvt_pk_f32_fp8((int)(wrd), false); \
  f32x2 hi_ = __builtin_amdgcn_cvt_pk_f32_fp8((int)(wrd), true); \
  acc0 = fmaf(lo_.x, wq, acc0); acc1 = fmaf(lo_.y, wq, acc1); \
  acc2 = fmaf(hi_.x, wq, acc2); acc3 = fmaf(hi_.y, wq, acc3); }

  if (deg <= 64){
    int sreg[4]; float wreg[4];
#pragma unroll
    for (int c = 0; c < 4; ++c){
      int idx = c*16 + j16;
      int s = (idx < deg) ? (int)csrc[e0 + idx] : 0;
      sreg[c] = s;
      wreg[c] = (idx < deg) ? lrelu(a_s[s*NH + h] + adst) : -3.0e38f;
    }
    float m = fmaxf(fmaxf(wreg[0], wreg[1]), fmaxf(wreg[2], wreg[3]));
#pragma unroll
    for (int o2 = 1; o2 < 16; o2 <<= 1) m = fmaxf(m, __shfl_xor(m, o2, 64));
    float se = 0.f;
#pragma unroll
    for (int c = 0; c < 4; ++c){
      int idx = c*16 + j16;
      float wc = (idx < deg) ? __expf(wreg[c] - m) : 0.f;
      wreg[c] = wc; se += wc;
    }
#pragma unroll
    for (int o2 = 1; o2 < 16; o2 <<= 1) se += __shfl_xor(se, o2, 64);
    float inv = 1.f / (se + 1e-16f);
#pragma unroll
    for (int c = 0; c < 4; ++c) lw[wv][h][c*16 + j16] = wreg[c] * inv;   // same-wave LDS, no barrier

#pragma unroll
    for (int c = 0; c < 4; ++c){
      int cbase = c*16;
      if (cbase < deg){
        int cnt = deg - cbase; if (cnt > 16) cnt = 16;
        int j2 = 0;
        for (; j2 + 8 <= cnt; j2 += 8){
          float4 wqa = *(const float4*)&lw[wv][h][cbase + j2];
          float4 wqb = *(const float4*)&lw[wv][h][cbase + j2 + 4];
          int s0 = rl(sreg[c], j2),   s1 = rl(sreg[c], j2+1);
          int s2 = rl(sreg[c], j2+2), s3 = rl(sreg[c], j2+3);
          int s4 = rl(sreg[c], j2+4), s5 = rl(sreg[c], j2+5);
          int s6 = rl(sreg[c], j2+6), s7 = rl(sreg[c], j2+7);
          u32 w0 = *(const u32*)(base + (size_t)(u32)s0*256);
          u32 w1 = *(const u32*)(base + (size_t)(u32)s1*256);
          u32 w2 = *(const u32*)(base + (size_t)(u32)s2*256);
          u32 w3 = *(const u32*)(base + (size_t)(u32)s3*256);
          u32 w4 = *(const u32*)(base + (size_t)(u32)s4*256);
          u32 w5 = *(const u32*)(base + (size_t)(u32)s5*256);
          u32 w6 = *(const u32*)(base + (size_t)(u32)s6*256);
          u32 w7 = *(const u32*)(base + (size_t)(u32)s7*256);
          GAT1_FMA8(w0, wqa.x) GAT1_FMA8(w1, wqa.y) GAT1_FMA8(w2, wqa.z) GAT1_FMA8(w3, wqa.w)
          GAT1_FMA8(w4, wqb.x) GAT1_FMA8(w5, wqb.y) GAT1_FMA8(w6, wqb.z) GAT1_FMA8(w7, wqb.w)
        }
        for (; j2 + 4 <= cnt; j2 += 4){
          float4 wq = *(const float4*)&lw[wv][h][cbase + j2];
          int s0 = rl(sreg[c], j2),   s1 = rl(sreg[c], j2+1);
          int s2 = rl(sreg[c], j2+2), s3 = rl(sreg[c], j2+3);
          u32 w0 = *(const u32*)(base + (size_t)(u32)s0*256);
          u32 w1 = *(const u32*)(base + (size_t)(u32)s1*256);
          u32 w2 = *(const u32*)(base + (size_t)(u32)s2*256);
          u32 w3 = *(const u32*)(base + (size_t)(u32)s3*256);
          GAT1_FMA8(w0, wq.x) GAT1_FMA8(w1, wq.y) GAT1_FMA8(w2, wq.z) GAT1_FMA8(w3, wq.w)
        }
        for (; j2 < cnt; ++j2){
          float wqs = lw[wv][h][cbase + j2];
          int s = rl(sreg[c], j2);
          u32 wd = *(const u32*)(base + (size_t)(u32)s*256);
          GAT1_FMA8(wd, wqs)
        }
      }
    }
  } else {
    // rare path: any degree
    float m = -3.0e38f;
    for (int i = e0 + j16; i < e1; i += 16){
      int s = csrc[i];
      m = fmaxf(m, lrelu(a_s[s*NH + h] + adst));
    }
#pragma unroll
    for (int o2 = 1; o2 < 16; o2 <<= 1) m = fmaxf(m, __shfl_xor(m, o2, 64));
    float se = 0.f;
    for (int i = e0 + j16; i < e1; i += 16){
      int s = csrc[i];
      se += __expf(lrelu(a_s[s*NH + h] + adst) - m);
    }
#pragma unroll
    for (int o2 = 1; o2 < 16; o2 <<= 1) se += __shfl_xor(se, o2, 64);
    float inv = 1.f / (se + 1e-16f);
    for (int i = e0; i < e1; ++i){
      int s = csrc[i];
      float wq = __expf(lrelu(a_s[s*NH + h] + adst) - m) * inv;
      u32 wd = *(const u32*)(base + (size_t)(u32)s*256);
      GAT1_FMA8(wd, wq)
    }
  }
  float4 bv = *(const float4*)&b1[4*l];
  u32 lo = pkbf16(lrelu(acc0 + bv.x), lrelu(acc1 + bv.y));
  u32 hi = pkbf16(lrelu(acc2 + bv.z), lrelu(acc3 + bv.w));
  *(uint2*)&h1outb[(size_t)n*256 + 4*l] = make_uint2(lo, hi);
}

// ---------- GAT layer-2 aggregation: wave = node; 8 edges in flight; bf16 out ----------
__global__ __launch_bounds__(256) void k_gat2(const u16* __restrict__ h2b, const float* __restrict__ a_s,
                       const float* __restrict__ a_d, const int* __restrict__ off,
                       const u16* __restrict__ csrc, const float* __restrict__ b2v,
                       u16* __restrict__ h2outb){
  int wv = threadIdx.x >> 6, l = threadIdx.x & 63;
  int n = blockIdx.x*4 + wv;      // wave == node
  if (n >= NN) return;
  int e0 = off[n], e1 = off[n+1], deg = e1 - e0;
  float adst = a_d[n];
  if (deg <= 64){
    int sA = 0; float alA = -3.0e38f;
    if (l < deg){
      sA = (int)csrc[e0 + l];
      alA = lrelu(a_s[sA] + adst);
    }
    float m = wmax(alA);
    float wA = (l < deg) ? __expf(alA - m) : 0.f;
    float se = wsum(wA);
    wA *= 1.f / (se + 1e-16f);
    float acc = 0.f;
    int idx = 0;
    for (; idx + 8 <= deg; idx += 8){
      int s0 = rl(sA, idx),   s1 = rl(sA, idx+1);
      int s2 = rl(sA, idx+2), s3 = rl(sA, idx+3);
      int s4 = rl(sA, idx+4), s5 = rl(sA, idx+5);
      int s6 = rl(sA, idx+6), s7 = rl(sA, idx+7);
      float w0 = rlf(wA, idx),   w1 = rlf(wA, idx+1);
      float w2 = rlf(wA, idx+2), w3 = rlf(wA, idx+3);
      float w4 = rlf(wA, idx+4), w5 = rlf(wA, idx+5);
      float w6 = rlf(wA, idx+6), w7 = rlf(wA, idx+7);
      float v0 = b2f(h2b[(size_t)(u32)s0*HD + l]);
      float v1 = b2f(h2b[(size_t)(u32)s1*HD + l]);
      float v2 = b2f(h2b[(size_t)(u32)s2*HD + l]);
      float v3 = b2f(h2b[(size_t)(u32)s3*HD + l]);
      float v4 = b2f(h2b[(size_t)(u32)s4*HD + l]);
      float v5 = b2f(h2b[(size_t)(u32)s5*HD + l]);
      float v6 = b2f(h2b[(size_t)(u32)s6*HD + l]);
      float v7 = b2f(h2b[(size_t)(u32)s7*HD + l]);
      acc = fmaf(v0, w0, acc); acc = fmaf(v1, w1, acc);
      acc = fmaf(v2, w2, acc); acc = fmaf(v3, w3, acc);
      acc = fmaf(v4, w4, acc); acc = fmaf(v5, w5, acc);
      acc = fmaf(v6, w6, acc); acc = fmaf(v7, w7, acc);
    }
    for (; idx < deg; ++idx){
      int s = rl(sA, idx);
      float w = rlf(wA, idx);
      acc = fmaf(b2f(h2b[(size_t)(u32)s*HD + l]), w, acc);
    }
    h2outb[(size_t)n*HD + l] = f2b(lrelu(acc + b2v[l]));
  } else {
    // rare path: any degree; lane = channel
    float m = -3.0e38f;
    for (int i = e0 + l; i < e1; i += 64){
      int s = csrc[i];
      m = fmaxf(m, lrelu(a_s[s] + adst));
    }
    m = wmax(m);
    float se = 0.f;
    for (int i = e0 + l; i < e1; i += 64){
      int s = csrc[i];
      se += __expf(lrelu(a_s[s] + adst) - m);
    }
    se = wsum(se);
    float inv = 1.f / (se + 1e-16f);
    float acc = 0.f;
    for (int i = e0; i < e1; ++i){
      int s = csrc[i];
      acc += b2f(h2b[(size_t)s*HD + l]) * __expf(lrelu(a_s[s] + adst) - m);
    }
    h2outb[(size_t)n*HD + l] = f2b(lrelu(acc*inv + b2v[l]));
  }
}

// ---------- pooling (bf16 input) + fused final MLP (last block) ----------

__global__ __launch_bounds__(256) void k_pool(const u16* __restrict__ h2outb, const int* __restrict__ batch,
                       float* __restrict__ gsum, unsigned* __restrict__ gmaxk, int* __restrict__ gcnt,
                       int* __restrict__ pdone,
                       const float* __restrict__ Wf1, const float* __restrict__ bf1,
                       const float* __restrict__ Wf2, const float* __restrict__ bf2,
                       float* __restrict__ out){
  __shared__ float ssum[NGR*HD];
  __shared__ unsigned smax[NGR*HD];
  __shared__ int scnt[NGR];
  int t = threadIdx.x;   // 256
  for (int i = t; i < NGR*HD; i += 256){ ssum[i] = 0.f; smax[i] = 0u; }
  if (t < NGR) scnt[t] = 0;
  __syncthreads();
  int wv = t >> 6, lane = t & 63;
  for (int n = blockIdx.x*4 + wv; n < NN; n += gridDim.x*4){
    int g = batch[n];
    float v = b2f(h2outb[(size_t)n*HD + lane]);
    atomicAdd(&ssum[g*HD + lane], v);
    atomicMax(&smax[g*HD + lane], f2key(v));
    if (lane == 0) atomicAdd(&scnt[g], 1);
  }
  __syncthreads();
  for (int i = t; i < NGR*HD; i += 256){
    atomicAdd(&gsum[i], ssum[i]);
    atomicMax(&gmaxk[i], smax[i]);
  }
  if (t < NGR) atomicAdd(&gcnt[t], scnt[t]);

  // last-block: fused final MLP + log_softmax (device-scope atomic reads for coherence)
  __threadfence();
  __shared__ int lastf;
  if (t == 0) lastf = (atomicAdd(pdone, 1) == (int)gridDim.x - 1) ? 1 : 0;
  __syncthreads();
  if (!lastf) return;

  __shared__ float sgv[4][HD];
  __shared__ float f1s[4][32];
  __shared__ float lgs[4][12];
  for (int g4 = 0; g4 < NGR; g4 += 4){
    int g = g4 + wv;
    float sum = atomicAdd(&gsum[g*HD + lane], 0.f);
    unsigned mk = atomicOr(&gmaxk[g*HD + lane], 0u);
    int c0 = (lane == 0) ? atomicAdd(&gcnt[g], 0) : 0;
    int c = __shfl(c0, 0, 64);
    float gv = sum / fmaxf((float)c, 1.f) + ((c > 0) ? key2f(mk) : 0.f);
    sgv[wv][lane] = gv;
    __syncthreads();
    if (lane < 32){
      float a = bf1[lane];
#pragma unroll
      for (int k = 0; k < HD; ++k) a += sgv[wv][k] * Wf1[k*32 + lane];
      f1s[wv][lane] = fmaxf(a, 0.f);
    }
    __syncthreads();
    if (lane < NCL){
      float a = bf2[lane];
#pragma unroll
      for (int k = 0; k < 32; ++k) a += f1s[wv][k] * Wf2[k*NCL + lane];
      lgs[wv][lane] = a;
    }
    __syncthreads();
    if (lane < NCL){
      float m = lgs[wv][0];
#pragma unroll
      for (int i2 = 1; i2 < NCL; ++i2) m = fmaxf(m, lgs[wv][i2]);
      float sx = 0.f;
#pragma unroll
      for (int i2 = 0; i2 < NCL; ++i2) sx += expf(lgs[wv][i2] - m);
      out[g*NCL + lane] = lgs[wv][lane] - m - logf(sx);
    }
    __syncthreads();
  }
}

extern "C" void kernel_launch(void* const* d_in, const int* in_sizes, int n_in,
                              void* d_out, int out_size, void* d_ws, size_t ws_size,
                              hipStream_t stream) {
  const float* x   = (const float*)d_in[0];
  const int*   ei  = (const int*)d_in[1];
  const int*   bat = (const int*)d_in[2];
  const float* Wp  = (const float*)d_in[3];
  const float* bp  = (const float*)d_in[4];
  const float* W1  = (const float*)d_in[5];
  const float* as1 = (const float*)d_in[6];
  const float* ad1 = (const float*)d_in[7];
  const float* b1  = (const float*)d_in[8];
  const float* W2  = (const float*)d_in[9];
  const float* as2 = (const float*)d_in[10];
  const float* ad2 = (const float*)d_in[11];
  const float* b2  = (const float*)d_in[12];
  const float* Wf1 = (const float*)d_in[13];
  const float* bf1 = (const float*)d_in[14];
  const float* Wf2 = (const float*)d_in[15];
  const float* bf2 = (const float*)d_in[16];
  float* out = (float*)d_out;

  char* base = (char*)d_ws;
  size_t o = 0;
  auto alloc = [&](size_t elems) -> char* {   // elems are 4-byte units
    char* p = base + o*4;
    o += (elems + 63) & ~(size_t)63;
    return p;
  };
  u8*    h1f8   = (u8*)alloc(3200000);       // [NN,256] fp8 e4m3 (12.8 MB)
  u16*   h1outb = (u16*)alloc(6400000);      // [NN,256] bf16
  u16*   h2b    = (u16*)alloc(1600000);      // [NN,64] bf16
  u16*   h2outb = (u16*)alloc(1600000);      // [NN,64] bf16
  float* a_s1   = (float*)alloc(200000);
  float* a_d1   = (float*)alloc(200000);
  float* a_s2   = (float*)alloc(50000);
  float* a_d2   = (float*)alloc(50000);
  int*   off    = (int*)alloc(50001);
  int*   bcnt   = (int*)alloc(NBK*ECH);      // 162,876
  int*   boff   = (int*)alloc(NBK*ECH);
  int*   btot   = (int*)alloc(256);
  int*   bb     = (int*)alloc(256);
  u32*   packed = (u32*)alloc(850000);       // [ET] (dstLow8<<16)|src
  u16*   csrc   = (u16*)alloc(425000);       // [ET] u16
  // ---- zero region (cleared by k_b1hist's extra block) ----
  char*  zstart = base + o*4;
  float* gsum   = (float*)alloc(NGR*HD);
  unsigned* gmaxk = (unsigned*)alloc(NGR*HD);
  int*   gcnt   = (int*)alloc(NGR);
  int*   pdone  = (int*)alloc(64);
  int    zcount = (int)(((base + o*4) - zstart) / 4);

  const int GB  = (NN + 127) / 128;     // 391 gemm blocks (2x64 rows each)
  const int WB  = (NN + 3) / 4;         // wave-per-node blocks

  // CSR build (no global atomics) ; +1 block zeroes gsum/gmaxk/gcnt/pdone
  k_b1hist<<<ECH + 1, 256, 0, stream>>>(ei, bcnt, (float*)zstart, zcount);
  k_bscana<<<NBK, 256, 0, stream>>>(bcnt, btot);
  k_bscanb<<<NBK, 256, 0, stream>>>(bcnt, btot, boff, bb);
  k_b1scat<<<ECH, 256, 0, stream>>>(ei, boff, packed);

  // fused: proj+feat1 GEMM chain (fp8 payload + dots) || per-bucket CSR finalize (off + csrc)
  k_phf2<<<GB + NBK, 256, 0, stream>>>(packed, btot, bb, off, csrc,
                                       x, Wp, bp, W1, as1, ad1, h1f8, a_s1, a_d1, GB);

  // GAT layer 1 (fp8 gather)
  k_gat1<<<WB, 256, 0, stream>>>(h1f8, a_s1, a_d1, off, csrc, b1, h1outb);

  // GAT layer 2
  k_feat2<<<GB, 256, 0, stream>>>(h1outb, W2, as2, ad2, h2b, a_s2, a_d2);
  k_gat2<<<WB, 256, 0, stream>>>(h2b, a_s2, a_d2, off, csrc, b2, h2outb);

  // pooling + fused final MLP + log_softmax
  k_pool<<<256, 256, 0, stream>>>(h2outb, bat, gsum, gmaxk, gcnt, pdone, Wf1, bf1, Wf2, bf2, out);
}

// Round 18
// 170.452 us; speedup vs baseline: 1.5810x; 1.5810x over previous
//
#include <hip/hip_runtime.h>
#include <math.h>

#define NN 50000
#define EE 800000
#define ET 850000    // EE + NN self loops
#define FIN 128
#define HD 64
#define NH 4
#define NGR 64
#define NCL 10
#define NEG 0.2f
#define NBK 196      // buckets = dst>>8
#define ECH 831      // edge chunks of 1024

typedef unsigned short u16;
typedef unsigned char u8;
typedef unsigned int u32;
typedef __attribute__((ext_vector_type(8))) short short8;
typedef __attribute__((ext_vector_type(4))) float f32x4;
typedef __attribute__((ext_vector_type(2))) float f32x2;

__device__ __forceinline__ float lrelu(float x){ return x > 0.f ? x : NEG * x; }

__device__ __forceinline__ float wsum(float v){
#pragma unroll
  for (int o = 32; o > 0; o >>= 1) v += __shfl_xor(v, o, 64);
  return v;
}
__device__ __forceinline__ float wmax(float v){
#pragma unroll
  for (int o = 32; o > 0; o >>= 1) v = fmaxf(v, __shfl_xor(v, o, 64));
  return v;
}
__device__ __forceinline__ int wsumi(int v){
#pragma unroll
  for (int o = 32; o > 0; o >>= 1) v += __shfl_xor(v, o, 64);
  return v;
}
__device__ __forceinline__ int esrc(const int* ei, int e){ return e < EE ? ei[e] : e - EE; }
__device__ __forceinline__ int edst(const int* ei, int e){ return e < EE ? ei[EE + e] : e - EE; }

__device__ __forceinline__ unsigned f2key(float f){
  unsigned u = __float_as_uint(f);
  return (u & 0x80000000u) ? ~u : (u | 0x80000000u);
}
__device__ __forceinline__ float key2f(unsigned k){
  return (k & 0x80000000u) ? __uint_as_float(k & 0x7fffffffu) : __uint_as_float(~k);
}

// bf16 pack (RNE) / unpack
__device__ __forceinline__ u16 f2b(float f){
  u32 u = __float_as_uint(f);
  u32 r = (u + 0x7FFFu + ((u >> 16) & 1u)) >> 16;
  return (u16)r;
}
__device__ __forceinline__ float b2f(u16 b){ return __uint_as_float(((u32)b) << 16); }
__device__ __forceinline__ u32 pkbf16(float lo, float hi){
  u32 r;
  asm("v_cvt_pk_bf16_f32 %0, %1, %2" : "=v"(r) : "v"(lo), "v"(hi));
  return r;
}
// fp8 e4m3 (OCP on gfx950) encode: low byte of packed cvt
__device__ __forceinline__ u8 f2fp8(float f){
  return (u8)__builtin_amdgcn_cvt_pk_fp8_f32(f, 0.f, 0, false);
}
// uniform readlane (idx may be runtime-uniform)
__device__ __forceinline__ int rl(int v, int idx){ return __builtin_amdgcn_readlane(v, idx); }
__device__ __forceinline__ float rlf(float v, int idx){
  return __uint_as_float((u32)__builtin_amdgcn_readlane((int)__float_as_uint(v), idx));
}

// ---------- CSR build pass 1a: per-chunk LDS bucket histogram || zero-init block ----------
__global__ __launch_bounds__(256) void k_b1hist(const int* __restrict__ ei, int* __restrict__ bcnt,
                                                float* __restrict__ zbase, int zcount){
  __shared__ int lc[NBK];
  int t = threadIdx.x, blk = blockIdx.x;
  if (blk >= ECH){
    // zero gsum/gmaxk/gcnt (visible to k_pool via kernel ordering)
    for (int i = t; i < zcount; i += 256) zbase[i] = 0.f;
    return;
  }
  for (int i = t; i < NBK; i += 256) lc[i] = 0;
  __syncthreads();
#pragma unroll
  for (int k = 0; k < 4; ++k){
    int e = blk*1024 + k*256 + t;
    if (e < ET) atomicAdd(&lc[edst(ei, e) >> 8], 1);
  }
  __syncthreads();
  for (int i = t; i < NBK; i += 256) bcnt[i*ECH + blk] = lc[i];
}

// ---------- pass 1b: bucket totals ----------
__global__ __launch_bounds__(256) void k_bscana(const int* __restrict__ bcnt, int* __restrict__ btot){
  int b = blockIdx.x, t = threadIdx.x;
  int s = 0;
  for (int j = t; j < ECH; j += 256) s += bcnt[b*ECH + j];
  s = wsumi(s);
  __shared__ int w4[4];
  if ((t & 63) == 0) w4[t >> 6] = s;
  __syncthreads();
  if (t == 0) btot[b] = w4[0] + w4[1] + w4[2] + w4[3];
}

// ---------- pass 1c: per-(bucket,chunk) global offsets + bucket bases ----------
__global__ __launch_bounds__(256) void k_bscanb(const int* __restrict__ bcnt, const int* __restrict__ btot,
                                                int* __restrict__ boff, int* __restrict__ bb){
  int b = blockIdx.x, t = threadIdx.x;
  int pv = (t < b) ? btot[t] : 0;       // NBK <= 256
  int r = wsumi(pv);
  __shared__ int w4[4];
  if ((t & 63) == 0) w4[t >> 6] = r;
  __syncthreads();
  int base = w4[0] + w4[1] + w4[2] + w4[3];
  if (t == 0) bb[b] = base;
  __shared__ int s[256];
  int carry = 0;
  for (int j0 = 0; j0 < ECH; j0 += 256){
    int j = j0 + t;
    int v = (j < ECH) ? bcnt[b*ECH + j] : 0;
    s[t] = v; __syncthreads();
    for (int d = 1; d < 256; d <<= 1){
      int xv = (t >= d) ? s[t-d] : 0;
      __syncthreads();
      s[t] += xv;
      __syncthreads();
    }
    int excl = s[t] - v;
    if (j < ECH) boff[b*ECH + j] = base + carry + excl;
    int tot = s[255];
    __syncthreads();
    carry += tot;
  }
}

// ---------- pass 1d: bucket-scatter edges into packed (LDS-atomic local rank only) ----------
__global__ __launch_bounds__(256) void k_b1scat(const int* __restrict__ ei, const int* __restrict__ boff,
                                                u32* __restrict__ packed){
  __shared__ int lpos[NBK];
  int t = threadIdx.x, blk = blockIdx.x;
  for (int i = t; i < NBK; i += 256) lpos[i] = boff[i*ECH + blk];
  __syncthreads();
#pragma unroll
  for (int k = 0; k < 4; ++k){
    int e = blk*1024 + k*256 + t;
    if (e < ET){
      int d = edst(ei, e);
      int s = esrc(ei, e);
      int slot = atomicAdd(&lpos[d >> 8], 1);
      packed[slot] = ((u32)(d & 255) << 16) | (u32)s;
    }
  }
}

// ---------- fused kernel: proj+feat1 GEMM chain || per-bucket CSR finalize ----------
__global__ __launch_bounds__(256) void k_phf2(
            const u32* __restrict__ packed, const int* __restrict__ btot, const int* __restrict__ bb,
            int* __restrict__ off, u16* __restrict__ csrc,
            const float* __restrict__ x, const float* __restrict__ Wp, const float* __restrict__ bp,
            const float* __restrict__ W1, const float* __restrict__ as1, const float* __restrict__ ad1,
            u8* __restrict__ h1f8, float* __restrict__ a_s, float* __restrict__ a_d, int gb){
  __shared__ u16 As[64*(FIN+8)];    // x staging, bf16, LDK1=136
  __shared__ u16 h0s[64*(HD+8)];    // h0 tile,   bf16, LDH=72
  __shared__ int hc[256];
  __shared__ int sc[256];
  __shared__ int pp[256];
  int t = threadIdx.x;
  int bid = blockIdx.x;
  if (bid >= gb){
    // ---- CSR finalize for bucket b ----
    int b = bid - gb;
    int e0 = bb[b];
    int cntb = btot[b];
    hc[t] = 0;
    __syncthreads();
    for (int i = t; i < cntb; i += 256){
      u32 p = packed[e0 + i];
      atomicAdd(&hc[p >> 16], 1);
    }
    __syncthreads();
    int v = hc[t];
    sc[t] = v; __syncthreads();
    for (int d = 1; d < 256; d <<= 1){
      int xv = (t >= d) ? sc[t-d] : 0;
      __syncthreads();
      sc[t] += xv;
      __syncthreads();
    }
    int excl = sc[t] - v;
    int node = b*256 + t;
    if (node < NN) off[node] = e0 + excl;
    if (b == 0 && t == 0) off[NN] = ET;
    pp[t] = excl;
    __syncthreads();
    for (int i = t; i < cntb; i += 256){
      u32 p = packed[e0 + i];
      int slot = atomicAdd(&pp[p >> 16], 1);
      csrc[(size_t)e0 + slot] = (u16)(p & 0xFFFFu);
    }
    return;
  }
  // ---- GEMM chain: h0 = relu(x@Wp+bp) (LDS); h1f8 = fp8(h0@W1); per-head dots ----
  constexpr int LDK1 = FIN + 8;   // 136
  constexpr int LDH  = HD + 8;    // 72
  int w = t >> 6, l = t & 63;
  int l16 = l & 15, kg = l >> 4;

  short8 bfp[4];
#pragma unroll
  for (int kt = 0; kt < 4; ++kt){
    short8 v;
#pragma unroll
    for (int j = 0; j < 8; ++j) v[j] = (short)f2b(Wp[(size_t)(kt*32 + kg*8 + j)*HD + w*16 + l16]);
    bfp[kt] = v;
  }
  short8 bf1[2*4];
#pragma unroll
  for (int kt = 0; kt < 2; ++kt)
#pragma unroll
    for (int nt = 0; nt < 4; ++nt){
      short8 v;
#pragma unroll
      for (int j = 0; j < 8; ++j) v[j] = (short)f2b(W1[(size_t)(kt*32 + kg*8 + j)*256 + w*64 + nt*16 + l16]);
      bf1[kt*4 + nt] = v;
    }
  float bv = bp[w*16 + l16];
  float asv[4], adv[4];
#pragma unroll
  for (int nt = 0; nt < 4; ++nt){
    asv[nt] = as1[w*64 + nt*16 + l16];
    adv[nt] = ad1[w*64 + nt*16 + l16];
  }

  for (int ch = 0; ch < 2; ++ch){
    int nb = (bid*2 + ch)*64;
    if (nb >= NN) break;
    __syncthreads();
    for (int u = t; u < 64*16; u += 256){
      int r = u >> 4, c = u & 15;
      int n = nb + r;
      uint4 v = make_uint4(0u,0u,0u,0u);
      if (n < NN){
        float4 f0 = *(const float4*)&x[(size_t)n*FIN + c*8];
        float4 f1 = *(const float4*)&x[(size_t)n*FIN + c*8 + 4];
        v = make_uint4(pkbf16(f0.x,f0.y), pkbf16(f0.z,f0.w), pkbf16(f1.x,f1.y), pkbf16(f1.z,f1.w));
      }
      *(uint4*)&As[r*LDK1 + c*8] = v;
    }
    __syncthreads();
#pragma unroll
    for (int rt = 0; rt < 4; ++rt){
      short8 afp[4];
#pragma unroll
      for (int kt = 0; kt < 4; ++kt)
        afp[kt] = *(const short8*)&As[(rt*16 + l16)*LDK1 + kt*32 + kg*8];
      f32x4 acc = (f32x4){0.f,0.f,0.f,0.f};
#pragma unroll
      for (int kt = 0; kt < 4; ++kt)
        acc = __builtin_amdgcn_mfma_f32_16x16x32_bf16(afp[kt], bfp[kt], acc, 0, 0, 0);
#pragma unroll
      for (int r4 = 0; r4 < 4; ++r4)
        h0s[(rt*16 + kg*4 + r4)*LDH + w*16 + l16] = f2b(fmaxf(acc[r4] + bv, 0.f));
    }
    __syncthreads();
#pragma unroll
    for (int rt = 0; rt < 4; ++rt){
      short8 af[2];
#pragma unroll
      for (int kt = 0; kt < 2; ++kt)
        af[kt] = *(const short8*)&h0s[(rt*16 + l16)*LDH + kt*32 + kg*8];
      f32x4 acc[4];
#pragma unroll
      for (int nt = 0; nt < 4; ++nt){
        acc[nt] = (f32x4){0.f,0.f,0.f,0.f};
#pragma unroll
        for (int kt = 0; kt < 2; ++kt)
          acc[nt] = __builtin_amdgcn_mfma_f32_16x16x32_bf16(af[kt], bf1[kt*4 + nt], acc[nt], 0, 0, 0);
      }
      int rbase = nb + rt*16 + kg*4;
#pragma unroll
      for (int nt = 0; nt < 4; ++nt)
#pragma unroll
        for (int r4 = 0; r4 < 4; ++r4){
          int n = rbase + r4;
          if (n < NN) h1f8[(size_t)n*256 + w*64 + nt*16 + l16] = f2fp8(acc[nt][r4]);
        }
#pragma unroll
      for (int r4 = 0; r4 < 4; ++r4){
        float ps = 0.f, pd = 0.f;
#pragma unroll
        for (int nt = 0; nt < 4; ++nt){
          ps = fmaf(acc[nt][r4], asv[nt], ps);
          pd = fmaf(acc[nt][r4], adv[nt], pd);
        }
#pragma unroll
        for (int o = 1; o < 16; o <<= 1){
          ps += __shfl_xor(ps, o, 64);
          pd += __shfl_xor(pd, o, 64);
        }
        int n = rbase + r4;
        if (l16 == 0 && n < NN){ a_s[n*NH + w] = ps; a_d[n*NH + w] = pd; }
      }
    }
  }
}

// ---------- MFMA GEMM body (used by feat2): C = A@B, bf16 in/out, fused layer-2 dots ----------
template<int K, int NOUT, int CPW>
__device__ __forceinline__ void gemm_body2(int bid, u16* As, float* sred,
            const u16* __restrict__ A, const float* __restrict__ Bf,
            const float* __restrict__ att_s, const float* __restrict__ att_d,
            u16* __restrict__ C, float* __restrict__ a_s, float* __restrict__ a_d){
  constexpr int KT = K/32;
  constexpr int LDK = K + 8;
  int t = threadIdx.x, w = t >> 6, l = t & 63;
  int c0 = w*CPW;
  int l16 = l & 15, kg = l >> 4;

  short8 bf[KT];
#pragma unroll
  for (int kt = 0; kt < KT; ++kt){
    int kbase = kt*32 + kg*8;
    int col = c0 + l16;
    short8 v;
#pragma unroll
    for (int j = 0; j < 8; ++j) v[j] = (short)f2b(Bf[(size_t)(kbase + j)*NOUT + col]);
    bf[kt] = v;
  }
  float asv = att_s[c0 + l16], adv = att_d[c0 + l16];

  for (int ch = 0; ch < 2; ++ch){
    int nb = (bid*2 + ch)*64;
    if (nb >= NN) break;
    __syncthreads();
    constexpr int UPR = K/8;
    for (int u = t; u < 64*UPR; u += 256){
      int r = u / UPR, c = u % UPR;
      int n = nb + r;
      uint4 v = make_uint4(0u,0u,0u,0u);
      if (n < NN) v = *(const uint4*)&A[(size_t)n*K + c*8];
      *(uint4*)&As[r*LDK + c*8] = v;
    }
    __syncthreads();
#pragma unroll
    for (int rt = 0; rt < 4; ++rt){
      short8 af[KT];
#pragma unroll
      for (int kt = 0; kt < KT; ++kt)
        af[kt] = *(const short8*)&As[(rt*16 + l16)*LDK + kt*32 + kg*8];
      f32x4 acc = (f32x4){0.f,0.f,0.f,0.f};
#pragma unroll
      for (int kt = 0; kt < KT; ++kt)
        acc = __builtin_amdgcn_mfma_f32_16x16x32_bf16(af[kt], bf[kt], acc, 0, 0, 0);
      int rbase = nb + rt*16 + kg*4;
#pragma unroll
      for (int r4 = 0; r4 < 4; ++r4){
        int n = rbase + r4;
        if (n < NN) C[(size_t)n*NOUT + c0 + l16] = f2b(acc[r4]);
      }
#pragma unroll
      for (int r4 = 0; r4 < 4; ++r4){
        float ps = acc[r4]*asv;
        float pd = acc[r4]*adv;
#pragma unroll
        for (int o = 1; o < 16; o <<= 1){
          ps += __shfl_xor(ps, o, 64);
          pd += __shfl_xor(pd, o, 64);
        }
        if (l16 == 0){
          int row = rt*16 + kg*4 + r4;
          sred[(w*64 + row)*2]     = ps;
          sred[(w*64 + row)*2 + 1] = pd;
        }
      }
    }
    __syncthreads();
    if (t < 64){
      int n = nb + t;
      if (n < NN){
        float s = sred[t*2] + sred[(64+t)*2] + sred[(128+t)*2] + sred[(192+t)*2];
        float d = sred[t*2+1] + sred[(64+t)*2+1] + sred[(128+t)*2+1] + sred[(192+t)*2+1];
        a_s[n] = s; a_d[n] = d;
      }
    }
  }
}

// ---------- feat2 GEMM with fused layer-2 dots ----------
__global__ __launch_bounds__(256) void k_feat2(const u16* __restrict__ h1outb, const float* __restrict__ W2,
            const float* __restrict__ as2, const float* __restrict__ ad2,
            u16* __restrict__ h2b, float* __restrict__ a_s, float* __restrict__ a_d){
  __shared__ u16 As[64*(256+8)];
  __shared__ float sred[4*64*2];
  gemm_body2<256, 64, 16>(blockIdx.x, As, sred, h1outb, W2, as2, ad2, h2b, a_s, a_d);
}

// ---------- GAT layer-1 aggregation: wave = node, 256B fp8 row/load, packed cvt ----------
__global__ __launch_bounds__(256) void k_gat1(const u8* __restrict__ h1f8, const float* __restrict__ a_s,
                       const float* __restrict__ a_d, const int* __restrict__ off,
                       const u16* __restrict__ csrc, const float* __restrict__ b1,
                       u16* __restrict__ h1outb){
  __shared__ float lw[4][4][68];   // [wave][head][64 + 4 pad]
  int wv = threadIdx.x >> 6, l = threadIdx.x & 63;
  int n = blockIdx.x*4 + wv;
  if (n >= NN) return;
  int e0 = off[n], e1 = off[n+1], deg = e1 - e0;
  int j16 = l & 15, h = l >> 4;
  float adst = a_d[n*NH + h];
  float acc0 = 0.f, acc1 = 0.f, acc2 = 0.f, acc3 = 0.f;
  const u8* base = h1f8 + 4*l;

#define GAT1_FMA8(wrd, wq) { \
  f32x2 lo_ = __builtin_amdgcn_cvt_pk_f32_fp8((int)(wrd), false); \
  f32x2 hi_ = __builtin_amdgcn_cvt_pk_f32_fp8((int)(wrd), true); \
  acc0 = fmaf(lo_.x, wq, acc0); acc1 = fmaf(lo_.y, wq, acc1); \
  acc2 = fmaf(hi_.x, wq, acc2); acc3 = fmaf(hi_.y, wq, acc3); }

  if (deg <= 64){
    int sreg[4]; float wreg[4];
#pragma unroll
    for (int c = 0; c < 4; ++c){
      int idx = c*16 + j16;
      int s = (idx < deg) ? (int)csrc[e0 + idx] : 0;
      sreg[c] = s;
      wreg[c] = (idx < deg) ? lrelu(a_s[s*NH + h] + adst) : -3.0e38f;
    }
    float m = fmaxf(fmaxf(wreg[0], wreg[1]), fmaxf(wreg[2], wreg[3]));
#pragma unroll
    for (int o2 = 1; o2 < 16; o2 <<= 1) m = fmaxf(m, __shfl_xor(m, o2, 64));
    float se = 0.f;
#pragma unroll
    for (int c = 0; c < 4; ++c){
      int idx = c*16 + j16;
      float wc = (idx < deg) ? __expf(wreg[c] - m) : 0.f;
      wreg[c] = wc; se += wc;
    }
#pragma unroll
    for (int o2 = 1; o2 < 16; o2 <<= 1) se += __shfl_xor(se, o2, 64);
    float inv = 1.f / (se + 1e-16f);
#pragma unroll
    for (int c = 0; c < 4; ++c) lw[wv][h][c*16 + j16] = wreg[c] * inv;   // same-wave LDS, no barrier

#pragma unroll
    for (int c = 0; c < 4; ++c){
      int cbase = c*16;
      if (cbase < deg){
        int cnt = deg - cbase; if (cnt > 16) cnt = 16;
        int j2 = 0;
        for (; j2 + 8 <= cnt; j2 += 8){
          float4 wqa = *(const float4*)&lw[wv][h][cbase + j2];
          float4 wqb = *(const float4*)&lw[wv][h][cbase + j2 + 4];
          int s0 = rl(sreg[c], j2),   s1 = rl(sreg[c], j2+1);
          int s2 = rl(sreg[c], j2+2), s3 = rl(sreg[c], j2+3);
          int s4 = rl(sreg[c], j2+4), s5 = rl(sreg[c], j2+5);
          int s6 = rl(sreg[c], j2+6), s7 = rl(sreg[c], j2+7);
          u32 w0 = *(const u32*)(base + (size_t)(u32)s0*256);
          u32 w1 = *(const u32*)(base + (size_t)(u32)s1*256);
          u32 w2 = *(const u32*)(base + (size_t)(u32)s2*256);
          u32 w3 = *(const u32*)(base + (size_t)(u32)s3*256);
          u32 w4 = *(const u32*)(base + (size_t)(u32)s4*256);
          u32 w5 = *(const u32*)(base + (size_t)(u32)s5*256);
          u32 w6 = *(const u32*)(base + (size_t)(u32)s6*256);
          u32 w7 = *(const u32*)(base + (size_t)(u32)s7*256);
          GAT1_FMA8(w0, wqa.x) GAT1_FMA8(w1, wqa.y) GAT1_FMA8(w2, wqa.z) GAT1_FMA8(w3, wqa.w)
          GAT1_FMA8(w4, wqb.x) GAT1_FMA8(w5, wqb.y) GAT1_FMA8(w6, wqb.z) GAT1_FMA8(w7, wqb.w)
        }
        for (; j2 + 4 <= cnt; j2 += 4){
          float4 wq = *(const float4*)&lw[wv][h][cbase + j2];
          int s0 = rl(sreg[c], j2),   s1 = rl(sreg[c], j2+1);
          int s2 = rl(sreg[c], j2+2), s3 = rl(sreg[c], j2+3);
          u32 w0 = *(const u32*)(base + (size_t)(u32)s0*256);
          u32 w1 = *(const u32*)(base + (size_t)(u32)s1*256);
          u32 w2 = *(const u32*)(base + (size_t)(u32)s2*256);
          u32 w3 = *(const u32*)(base + (size_t)(u32)s3*256);
          GAT1_FMA8(w0, wq.x) GAT1_FMA8(w1, wq.y) GAT1_FMA8(w2, wq.z) GAT1_FMA8(w3, wq.w)
        }
        for (; j2 < cnt; ++j2){
          float wqs = lw[wv][h][cbase + j2];
          int s = rl(sreg[c], j2);
          u32 wd = *(const u32*)(base + (size_t)(u32)s*256);
          GAT1_FMA8(wd, wqs)
        }
      }
    }
  } else {
    // rare path: any degree
    float m = -3.0e38f;
    for (int i = e0 + j16; i < e1; i += 16){
      int s = csrc[i];
      m = fmaxf(m, lrelu(a_s[s*NH + h] + adst));
    }
#pragma unroll
    for (int o2 = 1; o2 < 16; o2 <<= 1) m = fmaxf(m, __shfl_xor(m, o2, 64));
    float se = 0.f;
    for (int i = e0 + j16; i < e1; i += 16){
      int s = csrc[i];
      se += __expf(lrelu(a_s[s*NH + h] + adst) - m);
    }
#pragma unroll
    for (int o2 = 1; o2 < 16; o2 <<= 1) se += __shfl_xor(se, o2, 64);
    float inv = 1.f / (se + 1e-16f);
    for (int i = e0; i < e1; ++i){
      int s = csrc[i];
      float wq = __expf(lrelu(a_s[s*NH + h] + adst) - m) * inv;
      u32 wd = *(const u32*)(base + (size_t)(u32)s*256);
      GAT1_FMA8(wd, wq)
    }
  }
  float4 bv = *(const float4*)&b1[4*l];
  u32 lo = pkbf16(lrelu(acc0 + bv.x), lrelu(acc1 + bv.y));
  u32 hi = pkbf16(lrelu(acc2 + bv.z), lrelu(acc3 + bv.w));
  *(uint2*)&h1outb[(size_t)n*256 + 4*l] = make_uint2(lo, hi);
}

// ---------- GAT layer-2 aggregation: wave = node; 8 edges in flight; bf16 out ----------
__global__ __launch_bounds__(256) void k_gat2(const u16* __restrict__ h2b, const float* __restrict__ a_s,
                       const float* __restrict__ a_d, const int* __restrict__ off,
                       const u16* __restrict__ csrc, const float* __restrict__ b2v,
                       u16* __restrict__ h2outb){
  int wv = threadIdx.x >> 6, l = threadIdx.x & 63;
  int n = blockIdx.x*4 + wv;      // wave == node
  if (n >= NN) return;
  int e0 = off[n], e1 = off[n+1], deg = e1 - e0;
  float adst = a_d[n];
  if (deg <= 64){
    int sA = 0; float alA = -3.0e38f;
    if (l < deg){
      sA = (int)csrc[e0 + l];
      alA = lrelu(a_s[sA] + adst);
    }
    float m = wmax(alA);
    float wA = (l < deg) ? __expf(alA - m) : 0.f;
    float se = wsum(wA);
    wA *= 1.f / (se + 1e-16f);
    float acc = 0.f;
    int idx = 0;
    for (; idx + 8 <= deg; idx += 8){
      int s0 = rl(sA, idx),   s1 = rl(sA, idx+1);
      int s2 = rl(sA, idx+2), s3 = rl(sA, idx+3);
      int s4 = rl(sA, idx+4), s5 = rl(sA, idx+5);
      int s6 = rl(sA, idx+6), s7 = rl(sA, idx+7);
      float w0 = rlf(wA, idx),   w1 = rlf(wA, idx+1);
      float w2 = rlf(wA, idx+2), w3 = rlf(wA, idx+3);
      float w4 = rlf(wA, idx+4), w5 = rlf(wA, idx+5);
      float w6 = rlf(wA, idx+6), w7 = rlf(wA, idx+7);
      float v0 = b2f(h2b[(size_t)(u32)s0*HD + l]);
      float v1 = b2f(h2b[(size_t)(u32)s1*HD + l]);
      float v2 = b2f(h2b[(size_t)(u32)s2*HD + l]);
      float v3 = b2f(h2b[(size_t)(u32)s3*HD + l]);
      float v4 = b2f(h2b[(size_t)(u32)s4*HD + l]);
      float v5 = b2f(h2b[(size_t)(u32)s5*HD + l]);
      float v6 = b2f(h2b[(size_t)(u32)s6*HD + l]);
      float v7 = b2f(h2b[(size_t)(u32)s7*HD + l]);
      acc = fmaf(v0, w0, acc); acc = fmaf(v1, w1, acc);
      acc = fmaf(v2, w2, acc); acc = fmaf(v3, w3, acc);
      acc = fmaf(v4, w4, acc); acc = fmaf(v5, w5, acc);
      acc = fmaf(v6, w6, acc); acc = fmaf(v7, w7, acc);
    }
    for (; idx < deg; ++idx){
      int s = rl(sA, idx);
      float w = rlf(wA, idx);
      acc = fmaf(b2f(h2b[(size_t)(u32)s*HD + l]), w, acc);
    }
    h2outb[(size_t)n*HD + l] = f2b(lrelu(acc + b2v[l]));
  } else {
    // rare path: any degree; lane = channel
    float m = -3.0e38f;
    for (int i = e0 + l; i < e1; i += 64){
      int s = csrc[i];
      m = fmaxf(m, lrelu(a_s[s] + adst));
    }
    m = wmax(m);
    float se = 0.f;
    for (int i = e0 + l; i < e1; i += 64){
      int s = csrc[i];
      se += __expf(lrelu(a_s[s] + adst) - m);
    }
    se = wsum(se);
    float inv = 1.f / (se + 1e-16f);
    float acc = 0.f;
    for (int i = e0; i < e1; ++i){
      int s = csrc[i];
      acc += b2f(h2b[(size_t)s*HD + l]) * __expf(lrelu(a_s[s] + adst) - m);
    }
    h2outb[(size_t)n*HD + l] = f2b(lrelu(acc*inv + b2v[l]));
  }
}

// ---------- pooling (bf16 input) ----------

__global__ void k_pool(const u16* __restrict__ h2outb, const int* __restrict__ batch,
                       float* __restrict__ gsum, unsigned* __restrict__ gmaxk, int* __restrict__ gcnt){
  __shared__ float ssum[NGR*HD];
  __shared__ unsigned smax[NGR*HD];
  __shared__ int scnt[NGR];
  int t = threadIdx.x;   // 256
  for (int i = t; i < NGR*HD; i += 256){ ssum[i] = 0.f; smax[i] = 0u; }
  if (t < NGR) scnt[t] = 0;
  __syncthreads();
  int wv = t >> 6, lane = t & 63;
  for (int n = blockIdx.x*4 + wv; n < NN; n += gridDim.x*4){
    int g = batch[n];
    float v = b2f(h2outb[(size_t)n*HD + lane]);
    atomicAdd(&ssum[g*HD + lane], v);
    atomicMax(&smax[g*HD + lane], f2key(v));
    if (lane == 0) atomicAdd(&scnt[g], 1);
  }
  __syncthreads();
  for (int i = t; i < NGR*HD; i += 256){
    atomicAdd(&gsum[i], ssum[i]);
    atomicMax(&gmaxk[i], smax[i]);
  }
  if (t < NGR) atomicAdd(&gcnt[t], scnt[t]);
}

// ---------- final MLP + log_softmax ----------

__global__ void k_final(const float* __restrict__ gsum, const unsigned* __restrict__ gmaxk,
                        const int* __restrict__ gcnt,
                        const float* __restrict__ Wf1, const float* __restrict__ bf1,
                        const float* __restrict__ Wf2, const float* __restrict__ bf2,
                        float* __restrict__ out){
  int g = blockIdx.x, t = threadIdx.x;  // 64 threads
  __shared__ float gv[HD];
  __shared__ float f1[32];
  __shared__ float lg[NCL];
  int c = gcnt[g];
  float dn = fmaxf((float)c, 1.f);
  float mean = gsum[g*HD + t] / dn;
  float mx = (c > 0) ? key2f(gmaxk[g*HD + t]) : 0.f;
  gv[t] = mean + mx;
  __syncthreads();
  if (t < 32){
    float a = bf1[t];
#pragma unroll
    for (int k = 0; k < HD; ++k) a += gv[k] * Wf1[k*32 + t];
    f1[t] = a > 0.f ? a : 0.f;
  }
  __syncthreads();
  if (t < NCL){
    float a = bf2[t];
#pragma unroll
    for (int k = 0; k < 32; ++k) a += f1[k] * Wf2[k*NCL + t];
    lg[t] = a;
  }
  __syncthreads();
  if (t < NCL){
    float m = lg[0];
#pragma unroll
    for (int i = 1; i < NCL; ++i) m = fmaxf(m, lg[i]);
    float s = 0.f;
#pragma unroll
    for (int i = 0; i < NCL; ++i) s += expf(lg[i] - m);
    out[g*NCL + t] = lg[t] - m - logf(s);
  }
}

extern "C" void kernel_launch(void* const* d_in, const int* in_sizes, int n_in,
                              void* d_out, int out_size, void* d_ws, size_t ws_size,
                              hipStream_t stream) {
  const float* x   = (const float*)d_in[0];
  const int*   ei  = (const int*)d_in[1];
  const int*   bat = (const int*)d_in[2];
  const float* Wp  = (const float*)d_in[3];
  const float* bp  = (const float*)d_in[4];
  const float* W1  = (const float*)d_in[5];
  const float* as1 = (const float*)d_in[6];
  const float* ad1 = (const float*)d_in[7];
  const float* b1  = (const float*)d_in[8];
  const float* W2  = (const float*)d_in[9];
  const float* as2 = (const float*)d_in[10];
  const float* ad2 = (const float*)d_in[11];
  const float* b2  = (const float*)d_in[12];
  const float* Wf1 = (const float*)d_in[13];
  const float* bf1 = (const float*)d_in[14];
  const float* Wf2 = (const float*)d_in[15];
  const float* bf2 = (const float*)d_in[16];
  float* out = (float*)d_out;

  char* base = (char*)d_ws;
  size_t o = 0;
  auto alloc = [&](size_t elems) -> char* {   // elems are 4-byte units
    char* p = base + o*4;
    o += (elems + 63) & ~(size_t)63;
    return p;
  };
  u8*    h1f8   = (u8*)alloc(3200000);       // [NN,256] fp8 e4m3 (12.8 MB)
  u16*   h1outb = (u16*)alloc(6400000);      // [NN,256] bf16
  u16*   h2b    = (u16*)alloc(1600000);      // [NN,64] bf16
  u16*   h2outb = (u16*)alloc(1600000);      // [NN,64] bf16
  float* a_s1   = (float*)alloc(200000);
  float* a_d1   = (float*)alloc(200000);
  float* a_s2   = (float*)alloc(50000);
  float* a_d2   = (float*)alloc(50000);
  int*   off    = (int*)alloc(50001);
  int*   bcnt   = (int*)alloc(NBK*ECH);      // 162,876
  int*   boff   = (int*)alloc(NBK*ECH);
  int*   btot   = (int*)alloc(256);
  int*   bb     = (int*)alloc(256);
  u32*   packed = (u32*)alloc(850000);       // [ET] (dstLow8<<16)|src
  u16*   csrc   = (u16*)alloc(425000);       // [ET] u16
  // ---- zero region (cleared by k_b1hist's extra block) ----
  char*  zstart = base + o*4;
  float* gsum   = (float*)alloc(NGR*HD);
  unsigned* gmaxk = (unsigned*)alloc(NGR*HD);
  int*   gcnt   = (int*)alloc(NGR);
  int    zcount = (int)(((base + o*4) - zstart) / 4);

  const int GB  = (NN + 127) / 128;     // 391 gemm blocks (2x64 rows each)
  const int WB  = (NN + 3) / 4;         // wave-per-node blocks

  // CSR build (no global atomics) ; +1 block zeroes gsum/gmaxk/gcnt
  k_b1hist<<<ECH + 1, 256, 0, stream>>>(ei, bcnt, (float*)zstart, zcount);
  k_bscana<<<NBK, 256, 0, stream>>>(bcnt, btot);
  k_bscanb<<<NBK, 256, 0, stream>>>(bcnt, btot, boff, bb);
  k_b1scat<<<ECH, 256, 0, stream>>>(ei, boff, packed);

  // fused: proj+feat1 GEMM chain (fp8 payload + dots) || per-bucket CSR finalize (off + csrc)
  k_phf2<<<GB + NBK, 256, 0, stream>>>(packed, btot, bb, off, csrc,
                                       x, Wp, bp, W1, as1, ad1, h1f8, a_s1, a_d1, GB);

  // GAT layer 1 (fp8 gather)
  k_gat1<<<WB, 256, 0, stream>>>(h1f8, a_s1, a_d1, off, csrc, b1, h1outb);

  // GAT layer 2
  k_feat2<<<GB, 256, 0, stream>>>(h1outb, W2, as2, ad2, h2b, a_s2, a_d2);
  k_gat2<<<WB, 256, 0, stream>>>(h2b, a_s2, a_d2, off, csrc, b2, h2outb);

  // pooling
  k_pool<<<256, 256, 0, stream>>>(h2outb, bat, gsum, gmaxk, gcnt);

  // head MLP + log_softmax
  k_final<<<NGR, 64, 0, stream>>>(gsum, gmaxk, gcnt, Wf1, bf1, Wf2, bf2, out);
}